// Round 7
// baseline (329.330 us; speedup 1.0000x reference)
//
#include <hip/hip_runtime.h>
#include <math.h>

// ---------------------------------------------------------------------------
// MPNNPropPred: N=20000 nodes, E=50000 edges, B=128 graphs, H=64,
// FEAT=28, N_TYPES=100, EDGE_DIM=5, MP_ITER=3, S2S_IT=4. All f32.
// R11: zero-global-atomic message passing via dst-ownership blocks.
//   Evidence chain: R6->R9 showed MP throughput scales ~linearly with waves
//   (atomic-op-rate bound, 3.2M dword-RMW/iter); R10 showed de-fusing root
//   just exposes serial time. So: kill the global atomics entirely.
//   - edges sorted DST-MAJOR (dcnt histogram + 1024-thread scan + scatter,
//     R8's machinery with the scan parallelized 20us -> ~2us)
//   - k_mp: block owns dsts [16b,16b+16): waves 5-pass their contiguous
//     edge span by type (lazy W col load per type-hit -> W reuse), msgs
//     ds_add_f32 into a 4KB LDS tile; barrier; root matvec + bias + tile
//     -> ONE plain coalesced store per node. No atomics, no zeroing.
//   k_setup keeps R9's fast edgemats/transposes/embed; + dcnt histogram.
//   8 dispatches: starts, setup, dscan, placeD, 3x mp, s2s.
// ---------------------------------------------------------------------------

#define NN 20000
#define NE 50000
#define NB 128
#define HD 64
#define NFEAT 28
#define NTYPES 100
#define EDIM 5
#define MPIT 3
#define S2SIT 4
#define RNG 16                     // dsts per k_mp block
#define NBLK_MP (NN / RNG)         // 1250 (divides exactly)
#define SMAX 224                   // nodes cached in LDS (max graph ~195)
#define HP (HD + 1)                // padded LDS row stride

__device__ __forceinline__ float sigm(float x) {
  return 1.0f / (1.0f + expf(-x));
}

// --- first dispatch: CSR starts for batch vector + zero dst counters ---
__global__ __launch_bounds__(256) void k_starts(
    const int* __restrict__ batch, int* __restrict__ gstart,
    int* __restrict__ dcnt, int* __restrict__ dcur) {
  int n = blockIdx.x * blockDim.x + threadIdx.x;
  if (n >= NN) return;
  dcnt[n] = 0;
  dcur[n] = 0;
  int b = batch[n];
  if (n == 0)
    for (int t = 0; t <= b; ++t) gstart[t] = 0;
  int bn = (n + 1 < NN) ? batch[n + 1] : NB;
  for (int t = b + 1; t <= bn; ++t) gstart[t] = n + 1;
}

// --- setup: independent jobs fused; grid 512x256 ---
__global__ __launch_bounds__(256) void k_setup(
    const float* __restrict__ feat, const int* __restrict__ ntype,
    const int* __restrict__ ei,
    const float* __restrict__ W_emb, const float* __restrict__ b_emb,
    const float* __restrict__ W_e1, const float* __restrict__ b_e1,
    const float* __restrict__ W_e2, const float* __restrict__ b_e2,
    const float* __restrict__ W_ih, const float* __restrict__ W_hh,
    float* __restrict__ Wty, float* __restrict__ hA,
    float* __restrict__ W_ihT, float* __restrict__ W_hhT,
    int* __restrict__ dcnt) {
  __shared__ float sv[EDIM][HD];       // relu(W_e1+b_e1) per type
  __shared__ float red[4][EDIM][HD];   // j-group partial sums
  const int tid = threadIdx.x;
  const int lane = tid & 63;
  const int wv = tid >> 6;
  const int blk = blockIdx.x;
  const int nblk = gridDim.x;
  const int nthr = nblk << 8;
  const int gtid = (blk << 8) + tid;
  const int gw = (blk << 2) + wv;
  const int nwave = nblk << 2;

  // 1) edge-type weight matrices, latency-robust (blocks 0..63):
  //    block = 64-wide m-chunk; thread (jg,l): 16 coalesced W_e2 loads,
  //    5 type-accumulators per load; 4-way LDS reduce. W_e2 read once.
  if (blk < 64) {
    int mbase = blk * 64;
    for (int idx = tid; idx < EDIM * HD; idx += 256) {
      int t = idx >> 6, j = idx & 63;
      float x = W_e1[t * HD + j] + b_e1[j];
      sv[t][j] = x > 0.f ? x : 0.f;
    }
    __syncthreads();
    int l = tid & 63, jg = tid >> 6;
    float acc[EDIM] = {0.f, 0.f, 0.f, 0.f, 0.f};
    #pragma unroll
    for (int jj = 0; jj < 16; ++jj) {
      int j = jg * 16 + jj;
      float w2 = W_e2[j * 4096 + mbase + l];   // coalesced, independent
      #pragma unroll
      for (int t = 0; t < EDIM; ++t) acc[t] = fmaf(sv[t][j], w2, acc[t]);
    }
    #pragma unroll
    for (int t = 0; t < EDIM; ++t) red[jg][t][l] = acc[t];
    __syncthreads();
    for (int idx = tid; idx < EDIM * HD; idx += 256) {
      int t = idx >> 6, m = idx & 63;
      float s = red[0][t][m] + red[1][t][m] + red[2][t][m] + red[3][t][m];
      Wty[t * 4096 + mbase + m] = s + b_e2[mbase + m];
    }
  }

  // 2) LSTM weight transposes (coalesced writes)
  for (int o = gtid; o < 2 * HD * 4 * HD; o += nthr)       // W_ihT [128][256]
    W_ihT[o] = W_ih[(o & 255) * 128 + (o >> 8)];
  for (int o = gtid; o < HD * 4 * HD; o += nthr)           // W_hhT [64][256]
    W_hhT[o] = W_hh[(o & 255) * 64 + (o >> 8)];

  // 3) node embedding: wave per node, feature weights hoisted to VGPRs
  {
    float wf[NFEAT];
    #pragma unroll
    for (int f = 0; f < NFEAT; ++f) wf[f] = W_emb[(NTYPES + f) * HD + lane];
    float bb = b_emb[lane];
    for (int n = gw; n < NN; n += nwave) {
      int nu = __builtin_amdgcn_readfirstlane(n);
      int t = __builtin_amdgcn_readfirstlane(ntype[nu]);
      const float* row = feat + nu * NFEAT;        // wave-uniform -> s_load
      float acc = bb + W_emb[t * HD + lane];
      #pragma unroll
      for (int f = 0; f < NFEAT; ++f) acc = fmaf(row[f], wf[f], acc);
      hA[nu * HD + lane] = acc;
    }
  }

  // 4) dst histogram (random 4B atomics over 80 KB; dcnt zeroed in k_starts)
  for (int e = gtid; e < NE; e += nthr)
    atomicAdd(&dcnt[ei[NE + e]], 1);
}

// --- exclusive scan of dcnt[NN] -> dstart[NN+1]; 1024-thread single block
//     (independent unrolled loads -> pipelined; ~2-3 us) ---
__global__ __launch_bounds__(1024) void k_dscan(
    const int* __restrict__ dcnt, int* __restrict__ dstart) {
  __shared__ int buf[1024];
  const int tid = threadIdx.x;
  const int CH = 20;                 // 1024*20 = 20480 >= NN
  int base = tid * CH;
  int loc[CH];
  int s = 0;
  #pragma unroll
  for (int i = 0; i < CH; ++i) {
    int n = base + i;
    loc[i] = (n < NN) ? dcnt[n] : 0;
    s += loc[i];
  }
  buf[tid] = s;
  __syncthreads();
  for (int off = 1; off < 1024; off <<= 1) {
    int x = (tid >= off) ? buf[tid - off] : 0;
    __syncthreads();
    buf[tid] += x;
    __syncthreads();
  }
  int run = buf[tid] - s;            // exclusive prefix of this chunk
  #pragma unroll
  for (int i = 0; i < CH; ++i) {
    int n = base + i;
    if (n < NN) dstart[n] = run;
    run += loc[i];
  }
  if (tid == 1023) dstart[NN] = run; // == NE
}

// --- scatter edges into dst-major order; pack (src | type<<16, dst) ---
__global__ __launch_bounds__(256) void k_placeD(
    const int* __restrict__ ei, const int* __restrict__ etype,
    const int* __restrict__ dstart, int* __restrict__ dcur,
    int2* __restrict__ sdD) {
  int e = blockIdx.x * 256 + threadIdx.x;
  if (e >= NE) return;
  int s = ei[e], d = ei[NE + e], t = etype[e];
  int r = atomicAdd(&dcur[d], 1);    // avg 2.5 per counter, low contention
  sdD[dstart[d] + r] = make_int2(s | (t << 16), d);
}

// --- one MP iteration, zero global atomics. Block owns dsts [16b,16b+16):
//     waves 5-pass their contiguous dst-major edge span by type (lazy W
//     column load per type-hit), ds_add msgs into LDS tile; barrier; root
//     matvec + bias + tile -> one plain store per node.
__global__ __launch_bounds__(256) void k_mp(
    const int2* __restrict__ sdD, const int* __restrict__ dstart,
    const float* __restrict__ Wty, const float* __restrict__ hsrc,
    float* __restrict__ htgt,
    const float* __restrict__ root, const float* __restrict__ bias) {
  __shared__ float tile[RNG * HD];   // 4 KB
  const int tid = threadIdx.x;
  const int lane = tid & 63;
  const int wv = tid >> 6;
  const int nbase = blockIdx.x * RNG;

  for (int i = tid; i < RNG * HD; i += 256) tile[i] = 0.f;
  int lo = dstart[nbase];            // wave-uniform s_loads
  int hi = dstart[nbase + RNG];
  __syncthreads();

  int len = hi - lo;
  int per = (len + 3) >> 2;
  int mylo = lo + wv * per;
  int myhi = mylo + per; if (myhi > hi) myhi = hi;

  float w[HD];
  for (int t = 0; t < EDIM; ++t) {   // 5-pass type sweep for W reuse
    bool wl = false;
    for (int p = mylo; p < myhi; ++p) {
      int ex = __builtin_amdgcn_readfirstlane(sdD[p].x);
      int ty = ex >> 16;
      if (ty != t) continue;
      if (!wl) {
        #pragma unroll
        for (int k = 0; k < HD; ++k) w[k] = Wty[t * 4096 + k * HD + lane];
        wl = true;
      }
      int s = ex & 0xFFFF;
      int d = __builtin_amdgcn_readfirstlane(sdD[p].y);
      const float* row = hsrc + s * HD;          // wave-uniform -> s_load
      float a0 = 0.f, a1 = 0.f, a2 = 0.f, a3 = 0.f;
      #pragma unroll
      for (int k = 0; k < HD; k += 4) {
        a0 = fmaf(row[k + 0], w[k + 0], a0);
        a1 = fmaf(row[k + 1], w[k + 1], a1);
        a2 = fmaf(row[k + 2], w[k + 2], a2);
        a3 = fmaf(row[k + 3], w[k + 3], a3);
      }
      atomicAdd(&tile[(d - nbase) * HD + lane], (a0 + a1) + (a2 + a3));  // ds_add
    }
  }
  __syncthreads();

  // root matvec + bias + accumulated messages; 4 dsts per wave, plain store
  #pragma unroll
  for (int k = 0; k < HD; ++k) w[k] = root[k * HD + lane];
  float bb = bias[lane];
  #pragma unroll
  for (int i = 0; i < RNG / 4; ++i) {
    int dl = wv * (RNG / 4) + i;
    int n = nbase + dl;
    const float* row = hsrc + n * HD;            // wave-uniform -> s_load
    float a0 = bb, a1 = 0.f, a2 = 0.f, a3 = 0.f;
    #pragma unroll
    for (int k = 0; k < HD; k += 4) {
      a0 = fmaf(row[k + 0], w[k + 0], a0);
      a1 = fmaf(row[k + 1], w[k + 1], a1);
      a2 = fmaf(row[k + 2], w[k + 2], a2);
      a3 = fmaf(row[k + 3], w[k + 3], a3);
    }
    htgt[n * HD + lane] = ((a0 + a1) + (a2 + a3)) + tile[dl * HD + lane];
  }
}

// --- Set2Set + output MLP, one block per graph (proven R4 body) ---
__global__ __launch_bounds__(256) void k_s2s(
    const float* __restrict__ h, const int* __restrict__ gstart,
    const float* __restrict__ W_ihT, const float* __restrict__ W_hhT,
    const float* __restrict__ b_ih, const float* __restrict__ b_hh,
    const float* __restrict__ W_o1, const float* __restrict__ b_o1,
    const float* __restrict__ W_o2, const float* __restrict__ b_o2,
    float* __restrict__ out) {
  __shared__ float hs[SMAX * HP];     // 58240 B, padded rows
  __shared__ float ebuf[SMAX];
  __shared__ float qstar[2 * HD];
  __shared__ float hxs[HD], cxs[HD], gates[4 * HD];
  __shared__ float redM[4], redS[4], redR[4][HD];
  __shared__ float hid[HD];
  int b = blockIdx.x;
  int tid = threadIdx.x;
  int lane = tid & 63, wv = tid >> 6;

  int st = gstart[b], en = gstart[b + 1];
  int cnt = en - st;
  int cached = cnt < SMAX ? cnt : SMAX;

  // stage node block into padded LDS (coalesced float4 global reads)
  int total = cached * HD;
  for (int base = tid * 4; base < total; base += 1024) {
    float4 v = *reinterpret_cast<const float4*>(h + st * HD + base);
    int n = base >> 6, k = base & 63;
    float* row = hs + n * HP + k;
    row[0] = v.x; row[1] = v.y; row[2] = v.z; row[3] = v.w;
  }
  if (tid < 2 * HD) qstar[tid] = 0.f;
  if (tid < HD) { hxs[tid] = 0.f; cxs[tid] = 0.f; }
  __syncthreads();

  for (int it = 0; it < S2SIT; ++it) {
    // LSTM gates via transposed weights (coalesced): tid = gate index
    float acc0 = b_ih[tid] + b_hh[tid], acc1 = 0.f;
    #pragma unroll 8
    for (int j = 0; j < 2 * HD; j += 2) {
      acc0 = fmaf(qstar[j],     W_ihT[j * 256 + tid],       acc0);
      acc1 = fmaf(qstar[j + 1], W_ihT[(j + 1) * 256 + tid], acc1);
    }
    #pragma unroll 8
    for (int j = 0; j < HD; j += 2) {
      acc0 = fmaf(hxs[j],     W_hhT[j * 256 + tid],       acc0);
      acc1 = fmaf(hxs[j + 1], W_hhT[(j + 1) * 256 + tid], acc1);
    }
    gates[tid] = acc0 + acc1;
    __syncthreads();
    if (tid < HD) {
      float ig = sigm(gates[tid]);
      float fg = sigm(gates[HD + tid]);
      float gg = tanhf(gates[2 * HD + tid]);
      float og = sigm(gates[3 * HD + tid]);
      float c = fmaf(fg, cxs[tid], ig * gg);
      cxs[tid] = c;
      hxs[tid] = og * tanhf(c);
    }
    __syncthreads();

    // pass 1: per-thread dot (thread = node), padded LDS rows
    float e = -1e30f;
    if (tid < cached) {
      const float* row = hs + tid * HP;
      float d0 = 0.f, d1 = 0.f;
      #pragma unroll 8
      for (int k = 0; k < HD; k += 2) {
        d0 = fmaf(row[k],     hxs[k],     d0);
        d1 = fmaf(row[k + 1], hxs[k + 1], d1);
      }
      e = d0 + d1;
      ebuf[tid] = e;
    }
    float m = e;
    #pragma unroll
    for (int off = 32; off; off >>= 1) m = fmaxf(m, __shfl_xor(m, off, 64));
    float qreg = hxs[lane];
    for (int n = cached + wv; n < cnt; n += 4) {   // overflow tail
      float ev = h[(st + n) * HD + lane] * qreg;
      #pragma unroll
      for (int off = 32; off; off >>= 1) ev += __shfl_xor(ev, off, 64);
      m = fmaxf(m, ev);
    }
    if (lane == 0) redM[wv] = m;
    __syncthreads();
    float M = fmaxf(fmaxf(redM[0], redM[1]), fmaxf(redM[2], redM[3]));

    // pass 2a: a = exp(e-M), per-wave partial sum
    float sp = 0.f;
    if (tid < cached) {
      float a = expf(ebuf[tid] - M);
      ebuf[tid] = a;
      sp = a;
    }
    #pragma unroll
    for (int off = 32; off; off >>= 1) sp += __shfl_xor(sp, off, 64);
    __syncthreads();   // ebuf(a) visible to all waves

    // pass 2b: r = sum_n a[n] * h_n  (lane = feature)
    float r = 0.f;
    for (int n = wv; n < cached; n += 4)
      r = fmaf(ebuf[n], hs[n * HP + lane], r);
    float s_tail = 0.f;
    for (int n = cached + wv; n < cnt; n += 4) {   // overflow tail
      float v = h[(st + n) * HD + lane];
      float ev = v * qreg;
      #pragma unroll
      for (int off = 32; off; off >>= 1) ev += __shfl_xor(ev, off, 64);
      float a = expf(ev - M);
      s_tail += a;
      r = fmaf(a, v, r);
    }
    if (lane == 0) redS[wv] = sp + s_tail;
    redR[wv][lane] = r;
    __syncthreads();
    if (tid < HD) {
      float S = redS[0] + redS[1] + redS[2] + redS[3];
      float R = redR[0][tid] + redR[1][tid] + redR[2][tid] + redR[3][tid];
      if (S == 0.f) S = 1.f;            // empty-graph guard (matches ref)
      qstar[tid] = hxs[tid];
      qstar[HD + tid] = R / S;
    }
    __syncthreads();
  }

  // output MLP: relu(qstar @ W_o1 + b_o1) @ W_o2 + b_o2
  if (tid < HD) {
    float acc = b_o1[tid];
    #pragma unroll 8
    for (int i = 0; i < 2 * HD; ++i)
      acc = fmaf(qstar[i], W_o1[i * HD + tid], acc);
    hid[tid] = acc > 0.f ? acc : 0.f;
  }
  __syncthreads();
  if (tid < HD) {
    float p = hid[tid] * W_o2[tid];
    #pragma unroll
    for (int off = 32; off; off >>= 1) p += __shfl_xor(p, off, 64);
    if (tid == 0) out[b] = p + b_o2[0];
  }
}

extern "C" void kernel_launch(void* const* d_in, const int* in_sizes, int n_in,
                              void* d_out, int out_size, void* d_ws, size_t ws_size,
                              hipStream_t stream) {
  const float* node_feat = (const float*)d_in[0];
  const int*   node_type = (const int*)d_in[1];
  const int*   edge_index= (const int*)d_in[2];
  const int*   edge_type = (const int*)d_in[3];
  const int*   batch     = (const int*)d_in[4];
  const float* W_emb     = (const float*)d_in[5];
  const float* b_emb     = (const float*)d_in[6];
  const float* W_e1      = (const float*)d_in[7];
  const float* b_e1      = (const float*)d_in[8];
  const float* W_e2      = (const float*)d_in[9];
  const float* b_e2      = (const float*)d_in[10];
  const float* roots     = (const float*)d_in[11];
  const float* conv_bias = (const float*)d_in[12];
  const float* W_ih      = (const float*)d_in[13];
  const float* W_hh      = (const float*)d_in[14];
  const float* b_ih      = (const float*)d_in[15];
  const float* b_hh      = (const float*)d_in[16];
  const float* W_o1      = (const float*)d_in[17];
  const float* b_o1      = (const float*)d_in[18];
  const float* W_o2      = (const float*)d_in[19];
  const float* b_o2      = (const float*)d_in[20];
  float* out = (float*)d_out;

  // workspace layout (floats/ints), base assumed 256B-aligned
  float* Wty   = (float*)d_ws;              // 5*4096
  float* hA    = Wty + EDIM * 4096;         // NN*64
  float* hB    = hA + NN * HD;              // NN*64
  float* W_ihT = hB + NN * HD;              // 128*256
  float* W_hhT = W_ihT + 2 * HD * 4 * HD;   // 64*256
  int2*  sdD   = (int2*)(W_hhT + HD * 4 * HD); // NE int2
  int*   gstart= (int*)(sdD + NE);          // NB+1 (pad to 136)
  int*   dcnt  = gstart + 136;              // NN
  int*   dcur  = dcnt + NN;                 // NN
  int*   dstart= dcur + NN;                 // NN+1

  k_starts<<<(NN + 255) / 256, 256, 0, stream>>>(batch, gstart, dcnt, dcur);
  k_setup<<<512, 256, 0, stream>>>(node_feat, node_type, edge_index,
                                   W_emb, b_emb, W_e1, b_e1, W_e2, b_e2,
                                   W_ih, W_hh, Wty, hA, W_ihT, W_hhT, dcnt);
  k_dscan<<<1, 1024, 0, stream>>>(dcnt, dstart);
  k_placeD<<<(NE + 255) / 256, 256, 0, stream>>>(edge_index, edge_type,
                                                 dstart, dcur, sdD);

  // ping-pong: hA -> hB -> hA -> hB  (every node fully rewritten each iter)
  const float* hcur = hA;
  float* hnxt = hB;
  for (int i = 0; i < MPIT; ++i) {
    k_mp<<<NBLK_MP, 256, 0, stream>>>(sdD, dstart, Wty, hcur, hnxt,
                                      roots + i * HD * HD, conv_bias + i * HD);
    const float* tmp = hnxt; hnxt = (float*)hcur; hcur = tmp;
  }

  k_s2s<<<NB, 256, 0, stream>>>(hcur, gstart, W_ihT, W_hhT, b_ih, b_hh,
                                W_o1, b_o1, W_o2, b_o2, out);
}

// Round 8
// 207.306 us; speedup vs baseline: 1.5886x; 1.5886x over previous
//
#include <hip/hip_runtime.h>
#include <math.h>

// ---------------------------------------------------------------------------
// MPNNPropPred: N=20000 nodes, E=50000 edges, B=128 graphs, H=64,
// FEAT=28, N_TYPES=100, EDGE_DIM=5, MP_ITER=3, S2S_IT=4. All f32.
// R12: R9 structure (best: 209 us) + vectorized edge-message inner loop.
//   R11 proved the msg pass is LATENCY-bound (60 us/iter with ZERO atomics,
//   VALU 18%, HBM 4%): per-edge serial s_load of random 256-B h rows never
//   pipelines (scalar path). Fix: stage all 7 h rows per wave as
//   INDEPENDENT coalesced vector loads (hv[j] = h[src_j*64+lane], all in
//   flight), then compute via v_readlane broadcast + FMA (no scalar cache,
//   no LDS). Type packed in src word (src | ty<<16); W col in VGPRs,
//   reloaded only at type switches (<=4 waves see one in the sorted array).
//   Everything else byte-identical to R9 (fused root+zero+msg, triple
//   buffer, fast edgemats, type-sort place, proven s2s).
// ---------------------------------------------------------------------------

#define NN 20000
#define NE 50000
#define NB 128
#define HD 64
#define NFEAT 28
#define NTYPES 100
#define EDIM 5
#define MPIT 3
#define S2SIT 4
#define NBLK_E ((NE + 255) / 256)  // 196 fixed-range edge blocks
#define SMAX 224                   // nodes cached in LDS (max graph ~195)
#define HP (HD + 1)                // padded LDS row stride
#define EPW 7                      // edges per wave in k_mp (8192 waves)

__device__ __forceinline__ float sigm(float x) {
  return 1.0f / (1.0f + expf(-x));
}

__device__ __forceinline__ float rdlane(float v, int l) {
  return __uint_as_float(__builtin_amdgcn_readlane(__float_as_uint(v), l));
}

// --- sentinel + CSR starts for sorted batch vector (first dispatch) ---
__global__ __launch_bounds__(256) void k_starts(
    const int* __restrict__ batch, int* __restrict__ gstart) {
  int n = blockIdx.x * blockDim.x + threadIdx.x;
  if (n >= NN) return;
  int b = batch[n];
  if (n == 0)
    for (int t = 0; t <= b; ++t) gstart[t] = 0;
  int bn = (n + 1 < NN) ? batch[n + 1] : NB;
  for (int t = b + 1; t <= bn; ++t) gstart[t] = n + 1;
}

// --- setup: independent jobs fused; grid 512x256 ---
__global__ __launch_bounds__(256) void k_setup(
    const float* __restrict__ feat, const int* __restrict__ ntype,
    const int* __restrict__ etype,
    const float* __restrict__ W_emb, const float* __restrict__ b_emb,
    const float* __restrict__ W_e1, const float* __restrict__ b_e1,
    const float* __restrict__ W_e2, const float* __restrict__ b_e2,
    const float* __restrict__ W_ih, const float* __restrict__ W_hh,
    float* __restrict__ Wty, float* __restrict__ hA, float* __restrict__ hB,
    float* __restrict__ W_ihT, float* __restrict__ W_hhT,
    int* __restrict__ bc) {
  __shared__ int wcc[4][EDIM];
  __shared__ float sv[EDIM][HD];       // relu(W_e1+b_e1) per type
  __shared__ float red[4][EDIM][HD];   // j-group partial sums
  const int tid = threadIdx.x;
  const int lane = tid & 63;
  const int wv = tid >> 6;
  const int blk = blockIdx.x;
  const int nblk = gridDim.x;
  const int nthr = nblk << 8;
  const int gtid = (blk << 8) + tid;
  const int gw = (blk << 2) + wv;
  const int nwave = nblk << 2;

  // 1) per-block edge-type counts (blocks 0..195), atomic-free
  if (blk < NBLK_E) {
    int e = (blk << 8) + tid;
    int ty = (e < NE) ? etype[e] : -1;
    #pragma unroll
    for (int t = 0; t < EDIM; ++t) {
      unsigned long long m = __ballot(ty == t);
      if (lane == 0) wcc[wv][t] = __popcll(m);
    }
    __syncthreads();
    if (tid < EDIM)
      bc[blk * EDIM + tid] = wcc[0][tid] + wcc[1][tid] + wcc[2][tid] + wcc[3][tid];
    __syncthreads();
  }

  // 2) edge-type weight matrices, latency-robust (blocks 196..259):
  //    block = 64-wide m-chunk; thread (jg,l): 16 coalesced W_e2 loads,
  //    5 type-accumulators per load; 4-way LDS reduce. W_e2 read once.
  if (blk >= NBLK_E && blk < NBLK_E + 64) {
    int mbase = (blk - NBLK_E) * 64;
    for (int idx = tid; idx < EDIM * HD; idx += 256) {
      int t = idx >> 6, j = idx & 63;
      float x = W_e1[t * HD + j] + b_e1[j];
      sv[t][j] = x > 0.f ? x : 0.f;
    }
    __syncthreads();
    int l = tid & 63, jg = tid >> 6;
    float acc[EDIM] = {0.f, 0.f, 0.f, 0.f, 0.f};
    #pragma unroll
    for (int jj = 0; jj < 16; ++jj) {
      int j = jg * 16 + jj;
      float w2 = W_e2[j * 4096 + mbase + l];   // coalesced, independent
      #pragma unroll
      for (int t = 0; t < EDIM; ++t) acc[t] = fmaf(sv[t][j], w2, acc[t]);
    }
    #pragma unroll
    for (int t = 0; t < EDIM; ++t) red[jg][t][l] = acc[t];
    __syncthreads();
    for (int idx = tid; idx < EDIM * HD; idx += 256) {
      int t = idx >> 6, m = idx & 63;
      float s = red[0][t][m] + red[1][t][m] + red[2][t][m] + red[3][t][m];
      Wty[t * 4096 + mbase + m] = s + b_e2[mbase + m];
    }
  }

  // 3) LSTM weight transposes (coalesced writes)
  for (int o = gtid; o < 2 * HD * 4 * HD; o += nthr)       // W_ihT [128][256]
    W_ihT[o] = W_ih[(o & 255) * 128 + (o >> 8)];
  for (int o = gtid; o < HD * 4 * HD; o += nthr)           // W_hhT [64][256]
    W_hhT[o] = W_hh[(o & 255) * 64 + (o >> 8)];

  // 4) node embedding: wave per node, feature weights hoisted to VGPRs
  {
    float wf[NFEAT];
    #pragma unroll
    for (int f = 0; f < NFEAT; ++f) wf[f] = W_emb[(NTYPES + f) * HD + lane];
    float bb = b_emb[lane];
    for (int n = gw; n < NN; n += nwave) {
      int nu = __builtin_amdgcn_readfirstlane(n);
      int t = __builtin_amdgcn_readfirstlane(ntype[nu]);
      const float* row = feat + nu * NFEAT;        // wave-uniform -> s_load
      float acc = bb + W_emb[t * HD + lane];
      #pragma unroll
      for (int f = 0; f < NFEAT; ++f) acc = fmaf(row[f], wf[f], acc);
      hA[nu * HD + lane] = acc;
    }
  }

  // 5) zero hB (target of first MP iteration)
  {
    float4 z = make_float4(0.f, 0.f, 0.f, 0.f);
    for (int i = gtid; i < NN * HD / 4; i += nthr)
      reinterpret_cast<float4*>(hB)[i] = z;
  }
}

// --- place edges grouped by type; block scan base from bc (proven R7).
//     Writes packed (src | ty<<16, dst) int2.
__global__ __launch_bounds__(256) void k_place(
    const int* __restrict__ etype, const int* __restrict__ ei,
    const int* __restrict__ bc, int2* __restrict__ sd) {
  __shared__ int s_base[EDIM];      // this block's placement base per type
  __shared__ int wc[4][EDIM];
  const int tid = threadIdx.x;
  const int lane = tid & 63;
  const int wv = tid >> 6;
  const int blk = blockIdx.x;

  // wave 0: per-type totals and prefix-below-blk from bc (L2-resident 4 KB)
  if (wv == 0) {
    int part[EDIM], tot[EDIM];
    #pragma unroll
    for (int t = 0; t < EDIM; ++t) { part[t] = 0; tot[t] = 0; }
    for (int b = lane; b < NBLK_E; b += 64) {
      #pragma unroll
      for (int t = 0; t < EDIM; ++t) {
        int x = bc[b * EDIM + t];
        tot[t] += x;
        if (b < blk) part[t] += x;
      }
    }
    #pragma unroll
    for (int t = 0; t < EDIM; ++t) {
      #pragma unroll
      for (int off = 32; off; off >>= 1) {
        tot[t]  += __shfl_xor(tot[t],  off, 64);
        part[t] += __shfl_xor(part[t], off, 64);
      }
    }
    if (lane == 0) {
      int run = 0;
      #pragma unroll
      for (int t = 0; t < EDIM; ++t) {
        s_base[t] = run + part[t];
        run += tot[t];
      }
    }
  }

  // all waves: ballot ranks within the block's fixed 256-edge range
  int e = (blk << 8) + tid;
  int ty = (e < NE) ? etype[e] : -1;
  int sv = 0, dv = 0;
  if (e < NE) { sv = ei[e]; dv = ei[NE + e]; }
  int rank = 0;
  #pragma unroll
  for (int t = 0; t < EDIM; ++t) {
    unsigned long long m = __ballot(ty == t);
    if (lane == 0) wc[wv][t] = __popcll(m);
    if (ty == t) rank = __popcll(m & ((1ull << lane) - 1ull));
  }
  __syncthreads();
  if (ty >= 0) {
    int base = s_base[ty];
    for (int w = 0; w < wv; ++w) base += wc[w][ty];
    sd[base + rank] = make_int2(sv | (ty << 16), dv);
  }
}

// --- one MP iteration: blocks 0..511 do root (atomicAdd into zeroed tgt)
//     + zero next target; blocks 512..2559 do edge messages with staged
//     vector loads + readlane broadcast (no scalar-path random gathers).
__global__ __launch_bounds__(256) void k_mp(
    const int2* __restrict__ sd,
    const float* __restrict__ Wty, const float* __restrict__ hsrc,
    float* __restrict__ htgt, float* __restrict__ hzero,
    const float* __restrict__ root, const float* __restrict__ bias) {
  const int lane = threadIdx.x & 63;
  const int wv = threadIdx.x >> 6;
  const int blk = blockIdx.x;

  if (blk < 512) {
    // NNConv root matvec + bias, atomicAdd into zero-initialized target
    float w[HD];
    #pragma unroll
    for (int k = 0; k < HD; ++k) w[k] = root[k * HD + lane];
    float bb = bias[lane];
    int rw = (blk << 2) + wv;                    // 0..2047
    for (int n = rw; n < NN; n += 2048) {
      int nu = __builtin_amdgcn_readfirstlane(n);
      const float* row = hsrc + nu * HD;         // wave-uniform -> s_load
      float a0 = bb, a1 = 0.f, a2 = 0.f, a3 = 0.f;
      #pragma unroll
      for (int k = 0; k < HD; k += 4) {
        a0 = fmaf(row[k + 0], w[k + 0], a0);
        a1 = fmaf(row[k + 1], w[k + 1], a1);
        a2 = fmaf(row[k + 2], w[k + 2], a2);
        a3 = fmaf(row[k + 3], w[k + 3], a3);
      }
      atomicAdd(&htgt[nu * HD + lane], (a0 + a1) + (a2 + a3));
    }
    // zero next iteration's target (overlaps with this phase's traffic)
    if (hzero) {
      float4 z = make_float4(0.f, 0.f, 0.f, 0.f);
      for (int i = (blk << 8) + threadIdx.x; i < NN * HD / 4; i += 512 * 256)
        reinterpret_cast<float4*>(hzero)[i] = z;
    }
  } else {
    // edge messages: wave handles EPW consecutive type-sorted edges
    int wid = ((blk - 512) << 2) + wv;           // 0..8191
    int beg = wid * EPW;
    if (beg >= NE) return;
    int len = NE - beg; if (len > EPW) len = EPW;

    // one per-lane load fetches the wave's edge records (lanes 0..len-1)
    int2 ed = sd[beg + (lane < len ? lane : len - 1)];

    // stage all h rows as independent coalesced vector loads (in flight)
    float hv[EPW];
    #pragma unroll
    for (int j = 0; j < EPW; ++j) {
      int sx = __builtin_amdgcn_readlane(ed.x, j < EPW ? j : 0);
      // j >= len reads lane len-1's record: valid address, result unused
      hv[j] = hsrc[(sx & 0xFFFF) * HD + lane];
    }

    int curt = -1;
    float w[HD];
    #pragma unroll
    for (int j = 0; j < EPW; ++j) {
      if (j >= len) break;
      int ex = __builtin_amdgcn_readlane(ed.x, j);
      int dj = __builtin_amdgcn_readlane(ed.y, j);
      int ty = ex >> 16;
      if (ty != curt) {                          // rare: <=4 waves switch
        curt = ty;
        #pragma unroll
        for (int k = 0; k < HD; ++k) w[k] = Wty[ty * 4096 + k * HD + lane];
      }
      float a0 = 0.f, a1 = 0.f, a2 = 0.f, a3 = 0.f;
      #pragma unroll
      for (int k = 0; k < HD; k += 4) {
        a0 = fmaf(rdlane(hv[j], k + 0), w[k + 0], a0);
        a1 = fmaf(rdlane(hv[j], k + 1), w[k + 1], a1);
        a2 = fmaf(rdlane(hv[j], k + 2), w[k + 2], a2);
        a3 = fmaf(rdlane(hv[j], k + 3), w[k + 3], a3);
      }
      atomicAdd(&htgt[dj * HD + lane], (a0 + a1) + (a2 + a3));
    }
  }
}

// --- Set2Set + output MLP, one block per graph (proven R4 body) ---
__global__ __launch_bounds__(256) void k_s2s(
    const float* __restrict__ h, const int* __restrict__ gstart,
    const float* __restrict__ W_ihT, const float* __restrict__ W_hhT,
    const float* __restrict__ b_ih, const float* __restrict__ b_hh,
    const float* __restrict__ W_o1, const float* __restrict__ b_o1,
    const float* __restrict__ W_o2, const float* __restrict__ b_o2,
    float* __restrict__ out) {
  __shared__ float hs[SMAX * HP];     // 58240 B, padded rows
  __shared__ float ebuf[SMAX];
  __shared__ float qstar[2 * HD];
  __shared__ float hxs[HD], cxs[HD], gates[4 * HD];
  __shared__ float redM[4], redS[4], redR[4][HD];
  __shared__ float hid[HD];
  int b = blockIdx.x;
  int tid = threadIdx.x;
  int lane = tid & 63, wv = tid >> 6;

  int st = gstart[b], en = gstart[b + 1];
  int cnt = en - st;
  int cached = cnt < SMAX ? cnt : SMAX;

  // stage node block into padded LDS (coalesced float4 global reads)
  int total = cached * HD;
  for (int base = tid * 4; base < total; base += 1024) {
    float4 v = *reinterpret_cast<const float4*>(h + st * HD + base);
    int n = base >> 6, k = base & 63;
    float* row = hs + n * HP + k;
    row[0] = v.x; row[1] = v.y; row[2] = v.z; row[3] = v.w;
  }
  if (tid < 2 * HD) qstar[tid] = 0.f;
  if (tid < HD) { hxs[tid] = 0.f; cxs[tid] = 0.f; }
  __syncthreads();

  for (int it = 0; it < S2SIT; ++it) {
    // LSTM gates via transposed weights (coalesced): tid = gate index
    float acc0 = b_ih[tid] + b_hh[tid], acc1 = 0.f;
    #pragma unroll 8
    for (int j = 0; j < 2 * HD; j += 2) {
      acc0 = fmaf(qstar[j],     W_ihT[j * 256 + tid],       acc0);
      acc1 = fmaf(qstar[j + 1], W_ihT[(j + 1) * 256 + tid], acc1);
    }
    #pragma unroll 8
    for (int j = 0; j < HD; j += 2) {
      acc0 = fmaf(hxs[j],     W_hhT[j * 256 + tid],       acc0);
      acc1 = fmaf(hxs[j + 1], W_hhT[(j + 1) * 256 + tid], acc1);
    }
    gates[tid] = acc0 + acc1;
    __syncthreads();
    if (tid < HD) {
      float ig = sigm(gates[tid]);
      float fg = sigm(gates[HD + tid]);
      float gg = tanhf(gates[2 * HD + tid]);
      float og = sigm(gates[3 * HD + tid]);
      float c = fmaf(fg, cxs[tid], ig * gg);
      cxs[tid] = c;
      hxs[tid] = og * tanhf(c);
    }
    __syncthreads();

    // pass 1: per-thread dot (thread = node), padded LDS rows
    float e = -1e30f;
    if (tid < cached) {
      const float* row = hs + tid * HP;
      float d0 = 0.f, d1 = 0.f;
      #pragma unroll 8
      for (int k = 0; k < HD; k += 2) {
        d0 = fmaf(row[k],     hxs[k],     d0);
        d1 = fmaf(row[k + 1], hxs[k + 1], d1);
      }
      e = d0 + d1;
      ebuf[tid] = e;
    }
    float m = e;
    #pragma unroll
    for (int off = 32; off; off >>= 1) m = fmaxf(m, __shfl_xor(m, off, 64));
    float qreg = hxs[lane];
    for (int n = cached + wv; n < cnt; n += 4) {   // overflow tail
      float ev = h[(st + n) * HD + lane] * qreg;
      #pragma unroll
      for (int off = 32; off; off >>= 1) ev += __shfl_xor(ev, off, 64);
      m = fmaxf(m, ev);
    }
    if (lane == 0) redM[wv] = m;
    __syncthreads();
    float M = fmaxf(fmaxf(redM[0], redM[1]), fmaxf(redM[2], redM[3]));

    // pass 2a: a = exp(e-M), per-wave partial sum
    float sp = 0.f;
    if (tid < cached) {
      float a = expf(ebuf[tid] - M);
      ebuf[tid] = a;
      sp = a;
    }
    #pragma unroll
    for (int off = 32; off; off >>= 1) sp += __shfl_xor(sp, off, 64);
    __syncthreads();   // ebuf(a) visible to all waves

    // pass 2b: r = sum_n a[n] * h_n  (lane = feature)
    float r = 0.f;
    for (int n = wv; n < cached; n += 4)
      r = fmaf(ebuf[n], hs[n * HP + lane], r);
    float s_tail = 0.f;
    for (int n = cached + wv; n < cnt; n += 4) {   // overflow tail
      float v = h[(st + n) * HD + lane];
      float ev = v * qreg;
      #pragma unroll
      for (int off = 32; off; off >>= 1) ev += __shfl_xor(ev, off, 64);
      float a = expf(ev - M);
      s_tail += a;
      r = fmaf(a, v, r);
    }
    if (lane == 0) redS[wv] = sp + s_tail;
    redR[wv][lane] = r;
    __syncthreads();
    if (tid < HD) {
      float S = redS[0] + redS[1] + redS[2] + redS[3];
      float R = redR[0][tid] + redR[1][tid] + redR[2][tid] + redR[3][tid];
      if (S == 0.f) S = 1.f;            // empty-graph guard (matches ref)
      qstar[tid] = hxs[tid];
      qstar[HD + tid] = R / S;
    }
    __syncthreads();
  }

  // output MLP: relu(qstar @ W_o1 + b_o1) @ W_o2 + b_o2
  if (tid < HD) {
    float acc = b_o1[tid];
    #pragma unroll 8
    for (int i = 0; i < 2 * HD; ++i)
      acc = fmaf(qstar[i], W_o1[i * HD + tid], acc);
    hid[tid] = acc > 0.f ? acc : 0.f;
  }
  __syncthreads();
  if (tid < HD) {
    float p = hid[tid] * W_o2[tid];
    #pragma unroll
    for (int off = 32; off; off >>= 1) p += __shfl_xor(p, off, 64);
    if (tid == 0) out[b] = p + b_o2[0];
  }
}

extern "C" void kernel_launch(void* const* d_in, const int* in_sizes, int n_in,
                              void* d_out, int out_size, void* d_ws, size_t ws_size,
                              hipStream_t stream) {
  const float* node_feat = (const float*)d_in[0];
  const int*   node_type = (const int*)d_in[1];
  const int*   edge_index= (const int*)d_in[2];
  const int*   edge_type = (const int*)d_in[3];
  const int*   batch     = (const int*)d_in[4];
  const float* W_emb     = (const float*)d_in[5];
  const float* b_emb     = (const float*)d_in[6];
  const float* W_e1      = (const float*)d_in[7];
  const float* b_e1      = (const float*)d_in[8];
  const float* W_e2      = (const float*)d_in[9];
  const float* b_e2      = (const float*)d_in[10];
  const float* roots     = (const float*)d_in[11];
  const float* conv_bias = (const float*)d_in[12];
  const float* W_ih      = (const float*)d_in[13];
  const float* W_hh      = (const float*)d_in[14];
  const float* b_ih      = (const float*)d_in[15];
  const float* b_hh      = (const float*)d_in[16];
  const float* W_o1      = (const float*)d_in[17];
  const float* b_o1      = (const float*)d_in[18];
  const float* W_o2      = (const float*)d_in[19];
  const float* b_o2      = (const float*)d_in[20];
  float* out = (float*)d_out;

  // workspace layout (floats/ints), base assumed 256B-aligned
  float* Wty   = (float*)d_ws;              // 5*4096
  float* hA    = Wty + EDIM * 4096;         // NN*64
  float* hB    = hA + NN * HD;              // NN*64
  float* hC    = hB + NN * HD;              // NN*64
  float* W_ihT = hC + NN * HD;              // 128*256
  float* W_hhT = W_ihT + 2 * HD * 4 * HD;   // 64*256
  int2*  sd    = (int2*)(W_hhT + HD * 4 * HD); // NE int2
  int*   gstart= (int*)(sd + NE);           // NB+1 (pad to 136)
  int*   bc    = gstart + 136;              // NBLK_E*EDIM

  k_starts<<<(NN + 255) / 256, 256, 0, stream>>>(batch, gstart);  // sentinel
  k_setup<<<512, 256, 0, stream>>>(node_feat, node_type, edge_type,
                                   W_emb, b_emb, W_e1, b_e1, W_e2, b_e2,
                                   W_ih, W_hh, Wty, hA, hB, W_ihT, W_hhT, bc);
  k_place<<<NBLK_E, 256, 0, stream>>>(edge_type, edge_index, bc, sd);

  // it 0: hA -> hB (zero hC) | it 1: hB -> hC (zero hA) | it 2: hC -> hA
  k_mp<<<2560, 256, 0, stream>>>(sd, Wty, hA, hB, hC,
                                 roots + 0 * HD * HD, conv_bias + 0 * HD);
  k_mp<<<2560, 256, 0, stream>>>(sd, Wty, hB, hC, hA,
                                 roots + 1 * HD * HD, conv_bias + 1 * HD);
  k_mp<<<2560, 256, 0, stream>>>(sd, Wty, hC, hA, (float*)0,
                                 roots + 2 * HD * HD, conv_bias + 2 * HD);

  k_s2s<<<NB, 256, 0, stream>>>(hA, gstart, W_ihT, W_hhT, b_ih, b_hh,
                                W_o1, b_o1, W_o2, b_o2, out);
}